// Round 7
// baseline (189.243 us; speedup 1.0000x reference)
//
#include <hip/hip_runtime.h>

typedef __attribute__((ext_vector_type(8))) short bf16x8;
typedef __attribute__((ext_vector_type(4))) float f32x4;
typedef unsigned short u16;

#define NTOK 2048
#define DDIM 1024
#define HDIM 4096
#define KEXP 8

#define BM 320   // covers any realistic expert count in ONE tile (counts ~256±15)
#define BK 64
#define LDSS 72  // LDS row stride in bf16 elems (144B): b128 reads 2-way banks (free)
#define NDESC 16

__device__ __forceinline__ u16 f2bf(float f) {
  union { float f; unsigned int u; } c; c.f = f;
  unsigned int u = c.u;
  return (u16)((u + 0x7FFFu + ((u >> 16) & 1u)) >> 16);  // RNE
}
__device__ __forceinline__ unsigned pk2(float a, float b) {
  return (unsigned)f2bf(a) | ((unsigned)f2bf(b) << 16);
}

// ---------------- routing: counting sort + tile worklist ----------------
__global__ void route_kernel(const float* __restrict__ cw, int* __restrict__ offs,
                             int* __restrict__ perm, float* __restrict__ wsel,
                             int* __restrict__ desc) {
  __shared__ int cnt[KEXP];
  __shared__ int base[KEXP];
  const int t = threadIdx.x;  // 256 threads, 8 tokens each
  if (t < KEXP) cnt[t] = 0;
  __syncthreads();
  int eid[8]; float wv[8];
  #pragma unroll
  for (int i = 0; i < 8; i++) {
    const int tok = t * 8 + i;
    const float* p = cw + tok * KEXP;
    int best = 0; float bw = p[0];
    #pragma unroll
    for (int k = 1; k < KEXP; k++) { float v = p[k]; if (v > bw) { bw = v; best = k; } }
    eid[i] = best; wv[i] = bw;
    atomicAdd(&cnt[best], 1);
  }
  __syncthreads();
  if (t == 0) {
    int s = 0, nd = 0;
    for (int k = 0; k < KEXP; k++) {
      const int ck = cnt[k];
      base[k] = s; offs[k] = s;
      for (int m0 = 0; m0 < ck && nd < NDESC; m0 += BM)
        desc[nd++] = (k << 12) | (s + m0);   // pack expert(3b) | slot0(12b)
      s += ck;
    }
    offs[KEXP] = s;
    for (; nd < NDESC; nd++) desc[nd] = -1;
  }
  __syncthreads();
  #pragma unroll
  for (int i = 0; i < 8; i++) {
    const int tok = t * 8 + i;
    const int pos = atomicAdd(&base[eid[i]], 1);
    perm[pos] = tok;
    wsel[pos] = wv[i];
  }
}

// ---------------- gather x rows into expert-sorted bf16 ----------------
__global__ void gather_x(const float* __restrict__ x, const int* __restrict__ perm,
                         u16* __restrict__ Xb) {
  const int slot = blockIdx.x;
  const int tok = perm[slot];
  const int t = threadIdx.x;  // 256
  float4 v = ((const float4*)(x + (size_t)tok * DDIM))[t];
  ushort4 o; o.x = f2bf(v.x); o.y = f2bf(v.y); o.z = f2bf(v.z); o.w = f2bf(v.w);
  ((ushort4*)(Xb + (size_t)slot * DDIM))[t] = o;
}

// ---------------- pass 1: H = silu(X@wg) * (X@wu) ----------------
// 512 thr = 8 waves. BM=320, BN=32, BK=64. Waves 0-3 compute G (vs wg),
// waves 4-7 compute U (vs wu); same A fragments; epilogue exchanges U via LDS.
// 2 blocks/CU: independent pipelines keep HBM streaming through barriers.
__global__ __launch_bounds__(512, 4) void gemm_swiglu(
    const u16* __restrict__ Xb,
    const float* __restrict__ wg, const float* __restrict__ wu,
    const int* __restrict__ offs, const int* __restrict__ desc,
    u16* __restrict__ Hb) {
  __shared__ u16 As[BM * LDSS];
  __shared__ u16 Bg[32 * LDSS];
  __shared__ u16 Bu[32 * LDSS];

  const int d = desc[blockIdx.y];
  if (d < 0) return;
  const int e = d >> 12;
  const int slot0 = d & 0xFFF;
  const int Msub = offs[e + 1] - slot0;
  const int n0 = blockIdx.x * 32;

  const int t = threadIdx.x;
  const int lane = t & 63;
  const int W = t >> 6;        // 0..7
  const int wm = W & 3;        // m-strip (80 rows)
  const bool isU = W >= 4;
  const int l15 = lane & 15;
  const int lhi = lane >> 4;

  // A staging (sync, Xb is L2-resident): 640 slots (row, 32-elem half) over 512 thr
  const int a_row1 = t >> 1;
  const int a_ck = (t & 1) * 32;
  const u16* a_src1 = Xb + (size_t)min(slot0 + a_row1, NTOK - 1) * DDIM + a_ck;
  u16* a_dst1 = As + a_row1 * LDSS + a_ck;
  const bool do_a2 = t < 128;
  const u16* a_src2 = Xb + (size_t)min(slot0 + a_row1 + 256, NTOK - 1) * DDIM + a_ck;
  u16* a_dst2 = As + (a_row1 + 256) * LDSS + a_ck;

  // B staging (reg-prefetch): t<256 -> Bg from wg, t>=256 -> Bu from wu.
  // thread -> n-row (tb&31), k-chunk (tb>>5)*8: 8 scalar f32 loads, one b128 write.
  const int tb = t & 255;
  const float* Wsrc = ((t < 256) ? wg : wu) + (size_t)e * DDIM * HDIM;
  const int b_n = tb & 31;
  const int b_kk = (tb >> 5) * 8;
  const float* b_src = Wsrc + (size_t)b_kk * HDIM + n0 + b_n;
  u16* b_dst = ((t < 256) ? Bg : Bu) + b_n * LDSS + b_kk;

  float br[8];
  f32x4 acc[5][2] = {};

  // prologue: issue B tile-0 loads
  #pragma unroll
  for (int i = 0; i < 8; i++) br[i] = b_src[(size_t)i * HDIM];

  #pragma unroll 1
  for (int it = 0; it < DDIM / BK; ++it) {
    const int k0 = it * BK;
    if (it) __syncthreads();   // B1: full fence (readers of prev tile done)
    // A: sync load + write
    {
      const uint4* s = (const uint4*)(a_src1 + k0);
      uint4 s0 = s[0], s1 = s[1], s2 = s[2], s3 = s[3];
      uint4* dd = (uint4*)a_dst1;
      dd[0] = s0; dd[1] = s1; dd[2] = s2; dd[3] = s3;
      if (do_a2) {
        const uint4* q = (const uint4*)(a_src2 + k0);
        uint4 q0 = q[0], q1 = q[1], q2 = q[2], q3 = q[3];
        uint4* d2 = (uint4*)a_dst2;
        d2[0] = q0; d2[1] = q1; d2[2] = q2; d2[3] = q3;
      }
    }
    // B: write current tile from prefetched regs
    {
      uint4 w;
      w.x = pk2(br[0], br[1]); w.y = pk2(br[2], br[3]);
      w.z = pk2(br[4], br[5]); w.w = pk2(br[6], br[7]);
      *(uint4*)b_dst = w;
    }
    // issue next-tile B loads; they stay in flight across B2
    if (it + 1 < DDIM / BK) {
      const float* bs = b_src + (size_t)(k0 + BK) * HDIM;
      #pragma unroll
      for (int i = 0; i < 8; i++) br[i] = bs[(size_t)i * HDIM];
    }
    asm volatile("s_waitcnt lgkmcnt(0)" ::: "memory");  // own ds_writes visible
    __builtin_amdgcn_sched_barrier(0);
    __builtin_amdgcn_s_barrier();                        // B2: NO vmcnt drain
    __builtin_amdgcn_sched_barrier(0);
    // compute current tile (each wave: its matrix only)
    const u16* Bmat = isU ? Bu : Bg;
    #pragma unroll
    for (int ks = 0; ks < 2; ks++) {
      const int kof = ks * 32 + lhi * 8;
      bf16x8 bf[2];
      #pragma unroll
      for (int fn = 0; fn < 2; fn++)
        bf[fn] = *(const bf16x8*)(Bmat + (fn * 16 + l15) * LDSS + kof);
      #pragma unroll
      for (int fm = 0; fm < 5; fm++) {
        bf16x8 af = *(const bf16x8*)(As + (wm * 80 + fm * 16 + l15) * LDSS + kof);
        #pragma unroll
        for (int fn = 0; fn < 2; fn++)
          acc[fm][fn] = __builtin_amdgcn_mfma_f32_16x16x32_bf16(af, bf[fn], acc[fm][fn], 0, 0, 0);
      }
    }
  }

  // epilogue: U-waves publish u via LDS (reuse As as f32, stride 33), G-waves combine.
  float* Ubuf = (float*)As;
  __syncthreads();
  if (isU) {
    #pragma unroll
    for (int fm = 0; fm < 5; fm++) {
      #pragma unroll
      for (int i = 0; i < 4; i++) {
        const int row = wm * 80 + fm * 16 + lhi * 4 + i;
        #pragma unroll
        for (int fn = 0; fn < 2; fn++)
          Ubuf[row * 33 + fn * 16 + l15] = acc[fm][fn][i];
      }
    }
  }
  __syncthreads();
  if (!isU) {
    #pragma unroll
    for (int fm = 0; fm < 5; fm++) {
      #pragma unroll
      for (int i = 0; i < 4; i++) {
        const int row = wm * 80 + fm * 16 + lhi * 4 + i;
        if (row < Msub) {
          const size_t base = (size_t)(slot0 + row) * HDIM + n0;
          #pragma unroll
          for (int fn = 0; fn < 2; fn++) {
            const float g = acc[fm][fn][i];
            const float u = Ubuf[row * 33 + fn * 16 + l15];
            const float h = (g / (1.0f + __expf(-g))) * u;
            Hb[base + fn * 16 + l15] = f2bf(h);
          }
        }
      }
    }
  }
}

// ---------------- pass 2: Y = (H @ wd) * wsel, split-K=4, scatter-add ----------------
// 512 thr = 8 waves (4m x 2n), BM=320, BN=64. 2 blocks/CU.
__global__ __launch_bounds__(512, 4) void gemm_down(
    const u16* __restrict__ Hb, const float* __restrict__ wd,
    const int* __restrict__ offs, const int* __restrict__ desc,
    const int* __restrict__ perm, const float* __restrict__ wsel,
    float* __restrict__ y) {
  __shared__ u16 As[BM * LDSS];
  __shared__ u16 Bs[64 * LDSS];

  const int d = desc[blockIdx.y];
  if (d < 0) return;
  const int e = d >> 12;
  const int slot0 = d & 0xFFF;
  const int Msub = offs[e + 1] - slot0;
  const int n0 = blockIdx.x * 64;
  const int kbase = blockIdx.z * (HDIM / 4);

  const float* Wd = wd + (size_t)e * HDIM * DDIM;

  const int t = threadIdx.x;
  const int lane = t & 63;
  const int W = t >> 6;
  const int wm = W >> 1;   // 4 m-strips of 80
  const int wn = W & 1;    // 2 n-strips of 32
  const int l15 = lane & 15;
  const int lhi = lane >> 4;

  const int a_row1 = t >> 1;
  const int a_ck = (t & 1) * 32;
  const u16* a_src1 = Hb + (size_t)min(slot0 + a_row1, NTOK - 1) * HDIM + kbase + a_ck;
  u16* a_dst1 = As + a_row1 * LDSS + a_ck;
  const bool do_a2 = t < 128;
  const u16* a_src2 = Hb + (size_t)min(slot0 + a_row1 + 256, NTOK - 1) * HDIM + kbase + a_ck;
  u16* a_dst2 = As + (a_row1 + 256) * LDSS + a_ck;

  // B staging: n-pair n2=(t&31)*2, k-chunk kk=(t>>5)*4: 4 float2 loads, 2 uint2 writes.
  const int b_n2 = (t & 31) * 2;
  const int b_kk = (t >> 5) * 4;
  const float* b_src = Wd + (size_t)(kbase + b_kk) * DDIM + n0 + b_n2;
  u16* b_dst = Bs + b_n2 * LDSS + b_kk;

  float2 br[4];
  f32x4 acc[5][2] = {};

  #pragma unroll
  for (int i = 0; i < 4; i++) br[i] = *(const float2*)(b_src + (size_t)i * DDIM);

  const int NIT = (HDIM / 4) / BK;  // 16
  #pragma unroll 1
  for (int it = 0; it < NIT; ++it) {
    const int k0 = it * BK;
    if (it) __syncthreads();   // B1
    {
      const uint4* s = (const uint4*)(a_src1 + k0);
      uint4 s0 = s[0], s1 = s[1], s2 = s[2], s3 = s[3];
      uint4* dd = (uint4*)a_dst1;
      dd[0] = s0; dd[1] = s1; dd[2] = s2; dd[3] = s3;
      if (do_a2) {
        const uint4* q = (const uint4*)(a_src2 + k0);
        uint4 q0 = q[0], q1 = q[1], q2 = q[2], q3 = q[3];
        uint4* d2 = (uint4*)a_dst2;
        d2[0] = q0; d2[1] = q1; d2[2] = q2; d2[3] = q3;
      }
    }
    {
      uint2 w0, w1;
      w0.x = pk2(br[0].x, br[1].x); w0.y = pk2(br[2].x, br[3].x);
      w1.x = pk2(br[0].y, br[1].y); w1.y = pk2(br[2].y, br[3].y);
      *(uint2*)b_dst = w0;
      *(uint2*)(b_dst + LDSS) = w1;
    }
    if (it + 1 < NIT) {
      const float* bs = b_src + (size_t)(k0 + BK) * DDIM;
      #pragma unroll
      for (int i = 0; i < 4; i++) br[i] = *(const float2*)(bs + (size_t)i * DDIM);
    }
    asm volatile("s_waitcnt lgkmcnt(0)" ::: "memory");
    __builtin_amdgcn_sched_barrier(0);
    __builtin_amdgcn_s_barrier();   // B2
    __builtin_amdgcn_sched_barrier(0);
    #pragma unroll
    for (int ks = 0; ks < 2; ks++) {
      const int kof = ks * 32 + lhi * 8;
      bf16x8 bf[2];
      #pragma unroll
      for (int fn = 0; fn < 2; fn++)
        bf[fn] = *(const bf16x8*)(Bs + (wn * 32 + fn * 16 + l15) * LDSS + kof);
      #pragma unroll
      for (int fm = 0; fm < 5; fm++) {
        bf16x8 af = *(const bf16x8*)(As + (wm * 80 + fm * 16 + l15) * LDSS + kof);
        #pragma unroll
        for (int fn = 0; fn < 2; fn++)
          acc[fm][fn] = __builtin_amdgcn_mfma_f32_16x16x32_bf16(af, bf[fn], acc[fm][fn], 0, 0, 0);
      }
    }
  }

  // epilogue: scale by routing weight, scatter-add (4 K-quarters, commutative)
  #pragma unroll
  for (int fm = 0; fm < 5; fm++) {
    #pragma unroll
    for (int i = 0; i < 4; i++) {
      const int row = wm * 80 + fm * 16 + lhi * 4 + i;
      if (row < Msub) {
        const int slot = slot0 + row;
        const int tok = perm[slot];
        const float w = wsel[slot];
        const size_t base = (size_t)tok * DDIM + n0 + wn * 32;
        #pragma unroll
        for (int fn = 0; fn < 2; fn++)
          atomicAdd(y + base + fn * 16 + l15, acc[fm][fn][i] * w);
      }
    }
  }
}

extern "C" void kernel_launch(void* const* d_in, const int* in_sizes, int n_in,
                              void* d_out, int out_size, void* d_ws, size_t ws_size,
                              hipStream_t stream) {
  const float* x  = (const float*)d_in[0];
  const float* cw = (const float*)d_in[1];
  const float* wg = (const float*)d_in[2];
  const float* wu = (const float*)d_in[3];
  const float* wd = (const float*)d_in[4];
  float* y = (float*)d_out;

  char* ws = (char*)d_ws;
  int* offs   = (int*)ws;                          // 16 ints
  int* desc   = (int*)(ws + 64);                   // 16 ints
  int* perm   = (int*)(ws + 128);                  // 2048 ints
  float* wsel = (float*)(ws + 128 + NTOK * 4);     // 2048 floats
  u16* Xb = (u16*)(ws + 32768);                                    // 4 MB
  u16* Hb = (u16*)(ws + 32768 + (size_t)NTOK * DDIM * 2);          // 16 MB

  hipMemsetAsync(d_out, 0, (size_t)NTOK * DDIM * sizeof(float), stream);
  route_kernel<<<1, 256, 0, stream>>>(cw, offs, perm, wsel, desc);
  gather_x<<<NTOK, 256, 0, stream>>>(x, perm, Xb);
  gemm_swiglu<<<dim3(HDIM / 32, NDESC), 512, 0, stream>>>(Xb, wg, wu, offs, desc, Hb);
  gemm_down<<<dim3(DDIM / 64, NDESC, 4), 512, 0, stream>>>(Hb, wd, offs, desc, perm, wsel, y);
}